// Round 4
// baseline (227.581 us; speedup 1.0000x reference)
//
#include <hip/hip_runtime.h>
#include <hip/hip_bf16.h>

#define IN_DIM 512
#define OUT_DIM 512

typedef unsigned short u16;
typedef __attribute__((ext_vector_type(4))) float f32x4;
typedef __attribute__((ext_vector_type(8))) __bf16 bf16x8;

// Direct global->LDS DMA, 16B per lane. LDS dest is wave-uniform base + lane*16.
#define GLD16(gp, lp) __builtin_amdgcn_global_load_lds(                       \
    (const __attribute__((address_space(1))) void*)(gp),                      \
    (__attribute__((address_space(3))) void*)(lp), 16, 0, 0)

__device__ __forceinline__ float softplus_f(float r) {
    return (r > 15.0f) ? r : log1pf(expf(r));
}

// ---------------------------------------------------------------------------
// Kernel 1: fold w = w_mu + softplus(w_rho)*w_eps -> bf16 [OUT][IN] (K-major),
//           b = b_mu + softplus(b_rho)*b_eps -> f32 [OUT], into workspace.
// ---------------------------------------------------------------------------
__global__ void prep_kernel(const float* __restrict__ wmu, const float* __restrict__ wrho,
                            const float* __restrict__ weps, const float* __restrict__ bmu,
                            const float* __restrict__ brho, const float* __restrict__ beps,
                            u16* __restrict__ wbf, float* __restrict__ bias) {
    int gid = blockIdx.x * 256 + threadIdx.x;
    int i4 = gid * 4;
    const float4 mu  = *(const float4*)(wmu + i4);
    const float4 rho = *(const float4*)(wrho + i4);
    const float4 ep  = *(const float4*)(weps + i4);
    union { __bf16 h[4]; uint2 u; } pk;
    pk.h[0] = (__bf16)(mu.x + softplus_f(rho.x) * ep.x);
    pk.h[1] = (__bf16)(mu.y + softplus_f(rho.y) * ep.y);
    pk.h[2] = (__bf16)(mu.z + softplus_f(rho.z) * ep.z);
    pk.h[3] = (__bf16)(mu.w + softplus_f(rho.w) * ep.w);
    *(uint2*)(wbf + i4) = pk.u;
    if (gid < OUT_DIM) {
        bias[gid] = bmu[gid] + softplus_f(brho[gid]) * beps[gid];
    }
}

// ---------------------------------------------------------------------------
// Kernel 2: y = x @ w^T + b, fused dropout.
// T3-min 2-phase pipeline with global_load_lds (hardware-async staging):
//   prologue: STAGE(buf0, t=0); barrier;
//   loop t:   STAGE(buf^1, t+1);  ds_read+cvt+MFMA on buf;  barrier;
// Grid 2048 (512 M x 4 N), 256 thr = 4 waves (2x2). Block 128x128, BK=32.
// LDS: A f32 [2][128][32] (16KB/buf) + B bf16 [2][128][32] (8KB/buf) = 48KB.
// A converted f32->bf16 at fragment read (no separate x pass, no ws risk).
// acc[m][n] = mfma(wf[n], xf[m], .) -> out row=l15 dim, col=lk*4+reg -> x4 epilogue.
// ---------------------------------------------------------------------------
__global__ __launch_bounds__(256, 3) void bayes_gemm_kernel(
    const float* __restrict__ x, const float* __restrict__ du,
    const u16* __restrict__ wbf, const float* __restrict__ bias,
    float* __restrict__ out)
{
    __shared__ float lA[2][128 * 32];   // 16 KB per buffer
    __shared__ u16   lB[2][128 * 32];   //  8 KB per buffer

    // XCD-aware swizzle (2048 % 8 == 0 -> bijective): each XCD gets contiguous
    // logical ids so the 4 N-siblings of an M-band share the x band in its L2.
    const int raw   = blockIdx.x;
    const int lid   = (raw & 7) * 256 + (raw >> 3);
    const int mband = lid >> 2;      // 0..511
    const int nband = lid & 3;       // 0..3

    const int tid  = threadIdx.x;
    const int lane = tid & 63;
    const int wv   = tid >> 6;
    const int wm   = wv >> 1;        // 0..1
    const int wn   = wv & 1;         // 0..1
    const int l15  = lane & 15;
    const int lk   = lane >> 4;      // 0..3

    const int row0 = mband * 128;
    const int colb = nband * 128;

    // ---- staging geometry (linear LDS, lane l writes base + l*16B)
    // A: iter i covers rows i*32 + wv*8 + (lane>>3), f32 col (lane&7)*4
    const int arow = wv * 8 + (lane >> 3);
    const float* gA = x + (size_t)(row0 + arow) * IN_DIM + (lane & 7) * 4;
    // B: iter i covers rows i*64 + wv*16 + (lane>>2), bf16 col (lane&3)*8
    const int brow = wv * 16 + (lane >> 2);
    const u16* gB = wbf + (size_t)(colb + brow) * IN_DIM + (lane & 3) * 8;

    f32x4 acc[4][4] = {};   // [m][n]

    auto stage = [&](int t, int buf) {
#pragma unroll
        for (int i = 0; i < 4; ++i)
            GLD16(gA + (size_t)i * 32 * IN_DIM + t * 32,
                  &lA[buf][i * 1024 + wv * 256]);
#pragma unroll
        for (int i = 0; i < 2; ++i)
            GLD16(gB + (size_t)i * 64 * IN_DIM + t * 32,
                  &lB[buf][i * 2048 + wv * 512]);
    };

    // ---- prologue
    stage(0, 0);
    __syncthreads();   // drains vmcnt, buf0 ready

#pragma unroll
    for (int t = 0; t < 16; ++t) {
        const int buf = t & 1;
        if (t + 1 < 16) stage(t + 1, buf ^ 1);   // async DMA, in flight across compute

        // ---- compute tile t
        bf16x8 wf[4];
#pragma unroll
        for (int n = 0; n < 4; ++n) {
            int r = wn * 64 + n * 16 + l15;
            wf[n] = *(const bf16x8*)&lB[buf][r * 32 + lk * 8];
        }
#pragma unroll
        for (int m = 0; m < 4; ++m) {
            int r = wm * 64 + m * 16 + l15;
            const float* pa = &lA[buf][r * 32 + lk * 8];
            float4 a0 = *(const float4*)pa;
            float4 a1 = *(const float4*)(pa + 4);
            bf16x8 xf;
            xf[0] = (__bf16)a0.x; xf[1] = (__bf16)a0.y;
            xf[2] = (__bf16)a0.z; xf[3] = (__bf16)a0.w;
            xf[4] = (__bf16)a1.x; xf[5] = (__bf16)a1.y;
            xf[6] = (__bf16)a1.z; xf[7] = (__bf16)a1.w;
#pragma unroll
            for (int n = 0; n < 4; ++n)
                acc[m][n] = __builtin_amdgcn_mfma_f32_16x16x32_bf16(
                    wf[n], xf, acc[m][n], 0, 0, 0);
        }

        __syncthreads();   // one drain per K-step: next buf staged, this buf free
    }

    // ---- epilogue: bias + inverted dropout, dwordx4 throughout
#pragma unroll
    for (int m = 0; m < 4; ++m) {
#pragma unroll
        for (int n = 0; n < 4; ++n) {
            const int colB = colb + wn * 64 + n * 16 + lk * 4;
            const float4 b4 = *(const float4*)(bias + colB);
            size_t off = (size_t)(row0 + wm * 64 + m * 16 + l15) * OUT_DIM + colB;
            const float4 u4 = *(const float4*)(du + off);
            float4 o;
            o.x = (acc[m][n][0] + b4.x) * ((u4.x >= 0.2f) ? 1.25f : 0.0f);
            o.y = (acc[m][n][1] + b4.y) * ((u4.y >= 0.2f) ? 1.25f : 0.0f);
            o.z = (acc[m][n][2] + b4.z) * ((u4.z >= 0.2f) ? 1.25f : 0.0f);
            o.w = (acc[m][n][3] + b4.w) * ((u4.w >= 0.2f) ? 1.25f : 0.0f);
            *(float4*)(out + off) = o;
        }
    }
}

extern "C" void kernel_launch(void* const* d_in, const int* in_sizes, int n_in,
                              void* d_out, int out_size, void* d_ws, size_t ws_size,
                              hipStream_t stream) {
    const float* x    = (const float*)d_in[0];
    const float* wmu  = (const float*)d_in[1];
    const float* wrho = (const float*)d_in[2];
    const float* bmu  = (const float*)d_in[3];
    const float* brho = (const float*)d_in[4];
    const float* weps = (const float*)d_in[5];
    const float* beps = (const float*)d_in[6];
    const float* du   = (const float*)d_in[7];
    float* out = (float*)d_out;

    u16*   wbf  = (u16*)d_ws;
    float* bias = (float*)((char*)d_ws + OUT_DIM * IN_DIM * sizeof(u16));

    prep_kernel<<<256, 256, 0, stream>>>(wmu, wrho, weps, bmu, brho, beps, wbf, bias);
    bayes_gemm_kernel<<<2048, 256, 0, stream>>>(x, du, wbf, bias, out);
}

// Round 5
// 126.662 us; speedup vs baseline: 1.7968x; 1.7968x over previous
//
#include <hip/hip_runtime.h>
#include <hip/hip_bf16.h>

#define IN_DIM 512
#define OUT_DIM 512

typedef unsigned short u16;
typedef __attribute__((ext_vector_type(4))) float f32x4;
typedef __attribute__((ext_vector_type(8))) __bf16 bf16x8;

// Direct global->LDS DMA, 16B per lane. LDS dest is wave-uniform base + lane*16.
#define GLD16(gp, lp) __builtin_amdgcn_global_load_lds(                       \
    (const __attribute__((address_space(1))) void*)(gp),                      \
    (__attribute__((address_space(3))) void*)(lp), 16, 0, 0)

__device__ __forceinline__ float softplus_f(float r) {
    return (r > 15.0f) ? r : log1pf(expf(r));
}

// ---------------------------------------------------------------------------
// Kernel 1: fold w = w_mu + softplus(w_rho)*w_eps -> bf16 [OUT][IN] (K-major),
//           b = b_mu + softplus(b_rho)*b_eps -> f32 [OUT], into workspace.
// ---------------------------------------------------------------------------
__global__ void prep_kernel(const float* __restrict__ wmu, const float* __restrict__ wrho,
                            const float* __restrict__ weps, const float* __restrict__ bmu,
                            const float* __restrict__ brho, const float* __restrict__ beps,
                            u16* __restrict__ wbf, float* __restrict__ bias) {
    int gid = blockIdx.x * 256 + threadIdx.x;
    int i4 = gid * 4;
    const float4 mu  = *(const float4*)(wmu + i4);
    const float4 rho = *(const float4*)(wrho + i4);
    const float4 ep  = *(const float4*)(weps + i4);
    union { __bf16 h[4]; uint2 u; } pk;
    pk.h[0] = (__bf16)(mu.x + softplus_f(rho.x) * ep.x);
    pk.h[1] = (__bf16)(mu.y + softplus_f(rho.y) * ep.y);
    pk.h[2] = (__bf16)(mu.z + softplus_f(rho.z) * ep.z);
    pk.h[3] = (__bf16)(mu.w + softplus_f(rho.w) * ep.w);
    *(uint2*)(wbf + i4) = pk.u;
    if (gid < OUT_DIM) {
        bias[gid] = bmu[gid] + softplus_f(brho[gid]) * beps[gid];
    }
}

// ---------------------------------------------------------------------------
// Kernel 2: y = x @ w^T + b, fused dropout.
// R4 structure (2-phase gload_lds pipeline) + rule-21 swizzle:
//   LDS dest linear; global SOURCE inverse-permuted per lane; reads permuted.
//   A[row][32f32]: chunk p = c ^ (row&7)        -> 2-way max on ds_read_b128
//   B[row][32bf16]: chunk p = c ^ ((row>>1)&3)  -> 2-way max
// Grid 2048 (512 M x 4 N), 256 thr = 4 waves (2x2). Block 128x128, BK=32.
// ---------------------------------------------------------------------------
__global__ __launch_bounds__(256, 3) void bayes_gemm_kernel(
    const float* __restrict__ x, const float* __restrict__ du,
    const u16* __restrict__ wbf, const float* __restrict__ bias,
    float* __restrict__ out)
{
    __shared__ float lA[2][128 * 32];   // 16 KB per buffer
    __shared__ u16   lB[2][128 * 32];   //  8 KB per buffer

    const int raw   = blockIdx.x;
    const int lid   = (raw & 7) * 256 + (raw >> 3);   // 2048 % 8 == 0 -> bijective
    const int mband = lid >> 2;      // 0..511
    const int nband = lid & 3;       // 0..3

    const int tid  = threadIdx.x;
    const int lane = tid & 63;
    const int wv   = tid >> 6;
    const int wm   = wv >> 1;        // 0..1
    const int wn   = wv & 1;         // 0..1
    const int l15  = lane & 15;
    const int lk   = lane >> 4;      // 0..3

    const int row0 = mband * 128;
    const int colb = nband * 128;

    // ---- staging geometry (linear LDS dest, inverse-swizzled global source)
    // A: lane l -> LDS row i*32 + wv*8 + (l>>3), chunk p=(l&7).
    //    stored(row,p) must hold global chunk c = p ^ (row&7) = (l&7)^(l>>3).
    const int arow  = wv * 8 + (lane >> 3);
    const int acswz = ((lane & 7) ^ (lane >> 3)) * 4;          // f32 col
    const float* gA = x + (size_t)(row0 + arow) * IN_DIM + acswz;
    // B: lane l -> LDS row i*64 + wv*16 + (l>>2), chunk p=(l&3).
    //    stored(row,p) holds c = p ^ ((row>>1)&3) = (l&3)^((l>>3)&3).
    const int brow  = wv * 16 + (lane >> 2);
    const int bcswz = ((lane & 3) ^ ((lane >> 3) & 3)) * 8;    // u16 col
    const u16* gB = wbf + (size_t)(colb + brow) * IN_DIM + bcswz;

    f32x4 acc[4][4] = {};   // [m][n]

    auto stage = [&](int t, int buf) {
#pragma unroll
        for (int i = 0; i < 4; ++i)
            GLD16(gA + (size_t)i * 32 * IN_DIM + t * 32,
                  &lA[buf][i * 1024 + wv * 256]);
#pragma unroll
        for (int i = 0; i < 2; ++i)
            GLD16(gB + (size_t)i * 64 * IN_DIM + t * 32,
                  &lB[buf][i * 2048 + wv * 512]);
    };

    // ---- prologue
    stage(0, 0);
    __syncthreads();

#pragma unroll
    for (int t = 0; t < 16; ++t) {
        const int buf = t & 1;
        if (t + 1 < 16) stage(t + 1, buf ^ 1);   // hardware-async, in flight across compute

        // ---- compute tile t (swizzled reads, 2-way max conflicts)
        bf16x8 wf[4];
#pragma unroll
        for (int n = 0; n < 4; ++n) {
            int r = wn * 64 + n * 16 + l15;
            int p = lk ^ ((l15 >> 1) & 3);
            wf[n] = *(const bf16x8*)&lB[buf][r * 32 + p * 8];
        }
#pragma unroll
        for (int m = 0; m < 4; ++m) {
            int r  = wm * 64 + m * 16 + l15;
            int p0 = (2 * lk)     ^ (l15 & 7);
            int p1 = (2 * lk + 1) ^ (l15 & 7);
            float4 a0 = *(const float4*)&lA[buf][r * 32 + p0 * 4];
            float4 a1 = *(const float4*)&lA[buf][r * 32 + p1 * 4];
            bf16x8 xf;
            xf[0] = (__bf16)a0.x; xf[1] = (__bf16)a0.y;
            xf[2] = (__bf16)a0.z; xf[3] = (__bf16)a0.w;
            xf[4] = (__bf16)a1.x; xf[5] = (__bf16)a1.y;
            xf[6] = (__bf16)a1.z; xf[7] = (__bf16)a1.w;
#pragma unroll
            for (int n = 0; n < 4; ++n)
                acc[m][n] = __builtin_amdgcn_mfma_f32_16x16x32_bf16(
                    wf[n], xf, acc[m][n], 0, 0, 0);
        }

        __syncthreads();   // next buf staged, this buf free for overwrite
    }

    // ---- epilogue: bias + inverted dropout, dwordx4 throughout
#pragma unroll
    for (int m = 0; m < 4; ++m) {
#pragma unroll
        for (int n = 0; n < 4; ++n) {
            const int colB = colb + wn * 64 + n * 16 + lk * 4;
            const float4 b4 = *(const float4*)(bias + colB);
            size_t off = (size_t)(row0 + wm * 64 + m * 16 + l15) * OUT_DIM + colB;
            const float4 u4 = *(const float4*)(du + off);
            float4 o;
            o.x = (acc[m][n][0] + b4.x) * ((u4.x >= 0.2f) ? 1.25f : 0.0f);
            o.y = (acc[m][n][1] + b4.y) * ((u4.y >= 0.2f) ? 1.25f : 0.0f);
            o.z = (acc[m][n][2] + b4.z) * ((u4.z >= 0.2f) ? 1.25f : 0.0f);
            o.w = (acc[m][n][3] + b4.w) * ((u4.w >= 0.2f) ? 1.25f : 0.0f);
            *(float4*)(out + off) = o;
        }
    }
}

extern "C" void kernel_launch(void* const* d_in, const int* in_sizes, int n_in,
                              void* d_out, int out_size, void* d_ws, size_t ws_size,
                              hipStream_t stream) {
    const float* x    = (const float*)d_in[0];
    const float* wmu  = (const float*)d_in[1];
    const float* wrho = (const float*)d_in[2];
    const float* bmu  = (const float*)d_in[3];
    const float* brho = (const float*)d_in[4];
    const float* weps = (const float*)d_in[5];
    const float* beps = (const float*)d_in[6];
    const float* du   = (const float*)d_in[7];
    float* out = (float*)d_out;

    u16*   wbf  = (u16*)d_ws;
    float* bias = (float*)((char*)d_ws + OUT_DIM * IN_DIM * sizeof(u16));

    prep_kernel<<<256, 256, 0, stream>>>(wmu, wrho, weps, bmu, brho, beps, wbf, bias);
    bayes_gemm_kernel<<<2048, 256, 0, stream>>>(x, du, wbf, bias, out);
}